// Round 14
// baseline (265.111 us; speedup 1.0000x reference)
//
#include <hip/hip_runtime.h>

#define HWSZ 65536   // 256*256
#define CCH  64

typedef __bf16 bf16x8 __attribute__((ext_vector_type(8)));
typedef __bf16 bf16x4 __attribute__((ext_vector_type(4)));
typedef float  f32x4  __attribute__((ext_vector_type(4)));

__device__ inline void gload_lds16(const void* g, void* l) {
    __builtin_amdgcn_global_load_lds(
        (const __attribute__((address_space(1))) void*)g,
        (__attribute__((address_space(3))) void*)l, 16, 0, 0);
}

// ===========================================================================
// Prep bodies (merged single launch). W layouts: ci-split + 2-rows-per-128B
// + inverse-swizzled (linear global_load_lds + swizzled read = conflict-low).
// ===========================================================================

__device__ void cvt_body(int cb, const float* __restrict__ src,
                         __bf16* __restrict__ dst)
{
    int p  = cb * 256 + threadIdx.x;
    int b  = p >> 16, hw = p & 65535;
    const float* sp = src + (((size_t)b * 64) << 16) + hw;
    __bf16* dp = dst + (size_t)p * 64;
    #pragma unroll
    for (int c8 = 0; c8 < 8; ++c8) {
        bf16x8 v8;
        #pragma unroll
        for (int j = 0; j < 8; ++j)
            v8[j] = (__bf16)sp[(size_t)(c8 * 8 + j) << 16];
        *(bf16x8*)(dp + c8 * 8) = v8;
    }
}

__device__ void prep3_body(int cb, const float* __restrict__ src,
                           __bf16* __restrict__ dst)
{
    int t = cb * 256 + threadIdx.x;
    if (t >= 2 * 9 * 2048) return;
    int j  = t & 7;
    int u  = (t >> 3) & 255;
    int q  = t >> 11;
    int k  = q % 9, ci = q / 9;
    int r  = u >> 3;
    int v  = (u & 7) ^ (r & 7);
    int o  = 2 * r + (v >> 2);
    int g  = v & 3;
    int i  = ci * 32 + g * 8 + j;
    dst[t] = (__bf16)src[((size_t)o * 64 + i) * 9 + k];
}

__device__ void prepF_body(int cb, const float* __restrict__ mt,
                           const float* __restrict__ aw, __bf16* __restrict__ dst)
{
    int t = cb * 256 + threadIdx.x;
    if (t >= 2 * 25 * 3072) return;
    int j  = t & 7;
    int u  = (t >> 3) % 384;
    int q  = t / 3072;
    int k  = q % 25, ci = q / 25;
    int r  = u >> 3;
    int v  = (u & 7) ^ (r & 7);
    int o  = 2 * r + (v >> 2);
    int g  = v & 3;
    int i  = ci * 32 + g * 8 + j;
    float val = 0.f;
    if (o < 64)      val = mt[((size_t)o * 64 + i) * 25 + k];
    else if (o < 73) val = aw[((size_t)(o - 64) * 64 + i) * 25 + k];
    dst[t] = (__bf16)val;
}

// prep super-kernel. Grid 2512.
__global__ __launch_bounds__(256) void k_prep(
    const float* x, const float* mask,
    const float* c1w, const float* c2w,
    const float* mt1w, const float* aw1w,
    const float* mt2w, const float* aw2w,
    __bf16* xh, __bf16* mh,
    __bf16* wbc1, __bf16* wbc2, __bf16* wbF1, __bf16* wbF2)
{
    int bid = blockIdx.x;
    if      (bid < 512)  cvt_body(bid, x, xh);
    else if (bid < 1024) cvt_body(bid - 512, mask, mh);
    else if (bid < 1168) prep3_body(bid - 1024, c1w, wbc1);
    else if (bid < 1312) prep3_body(bid - 1168, c2w, wbc2);
    else if (bid < 1912) prepF_body(bid - 1312, mt1w, aw1w, wbF1);
    else                 prepF_body(bid - 1912, mt2w, aw2w, wbF2);
}

// ---------------------------------------------------------------------------
// MFMA implicit-GEMM conv body, ci-split (32 in-ch per phase). LDS rows =
// 128B (2 pixels / 2 W-rows x 32ch), XOR-swizzled 16B slots. W staged via
// async global_load_lds double-buffer, counted vmcnt, raw barriers, setprio
// around the MFMA cluster. smem layout: lx | lw0 | lw1 | lb.
// ---------------------------------------------------------------------------
template<int KSZ, int MFT, int RELU, int EPI>
__device__ void mconv_body(char* smem, int bx, int by, int b,
    const __bf16* __restrict__ xh, const __bf16* __restrict__ wb,
    const float* __restrict__ bias, const float* __restrict__ bias2,
    float* __restrict__ outf, __bf16* __restrict__ outh,
    float* __restrict__ out2)
{
    constexpr int PAD   = KSZ / 2;
    constexpr int TW    = 16 + 2 * PAD;
    constexpr int NPIX  = TW * TW;
    constexpr int KK    = KSZ * KSZ;
    constexpr int SROWS = (MFT == 5) ? 96 : 64;
    constexpr int SLICE = SROWS * 64;       // bytes per (ci,k) W slice
    constexpr int NPIX2 = NPIX / 2;

    __bf16* lx  = (__bf16*)smem;                  // NPIX2 * 128B rows
    __bf16* lw0 = lx + NPIX2 * 64;                // SROWS*32
    __bf16* lw1 = lw0 + SROWS * 32;
    float*  lb  = (float*)(lw1 + SROWS * 32);     // 80 floats

    const int t    = threadIdx.x;
    const int w0   = bx * 16, h0 = by * 16;
    const int wvv  = t >> 6;
    const int lane = t & 63;
    const int px   = lane & 15;
    const int g    = lane >> 4;

    auto STAGE = [&](int ci, int k, __bf16* lbuf) {
        const char* gs = (const char*)wb + (size_t)(ci * KK + k) * SLICE;
        if constexpr (MFT == 5) {
            if (wvv < 3) {
                #pragma unroll
                for (int r = 0; r < 2; ++r) {
                    int ub = wvv * 128 + r * 64;
                    gload_lds16(gs + (ub + lane) * 16, (char*)lbuf + ub * 16);
                }
            }
        } else {
            int ub = wvv * 64;
            gload_lds16(gs + (ub + lane) * 16, (char*)lbuf + ub * 16);
        }
    };

    f32x4 acc[MFT][4];
    #pragma unroll
    for (int m = 0; m < MFT; ++m)
        #pragma unroll
        for (int nf = 0; nf < 4; ++nf)
            acc[m][nf] = (f32x4){0.f, 0.f, 0.f, 0.f};

    bf16x8 zv;
    #pragma unroll
    for (int j = 0; j < 8; ++j) zv[j] = (__bf16)0.f;

    for (int ci = 0; ci < 2; ++ci) {
        if (ci) __syncthreads();             // all readers of lx/lw done
        STAGE(ci, 0, lw0);
        STAGE(ci, 1, lw1);
        if (ci == 0) {
            if (t < 64) lb[t] = bias[t];
            if constexpr (MFT == 5) {
                if (t >= 64 && t < 80) lb[t] = (t - 64 < 9) ? bias2[t - 64] : 0.f;
            }
        }

        // ---- stage x half-channels (2-pixel-packed swizzled rows)
        constexpr int XITER = (NPIX * 4 + 255) / 256;
        #pragma unroll
        for (int xi = 0; xi < XITER; ++xi) {
            int e = xi * 256 + t;
            if (e < NPIX * 4) {
                int pix = e >> 2, c4 = e & 3;
                int sy = pix / TW, sx = pix - sy * TW;
                int gy = h0 + sy - PAD, gx = w0 + sx - PAD;
                bool ok = (unsigned)gy < 256u && (unsigned)gx < 256u;
                bf16x8 v8 = zv;
                if (ok) v8 = *(const bf16x8*)(xh + ((((size_t)b << 16) + gy * 256 + gx) << 6)
                                              + ci * 32 + c4 * 8);
                int row = pix >> 1;
                int off = row * 128 + (((((pix & 1) << 2) + c4) ^ (row & 7)) << 4);
                *(bf16x8*)((char*)lx + off) = v8;
            }
        }
        __syncthreads();                     // x half + W slices 0,1 resident

        #pragma unroll
        for (int k = 0; k < KK; ++k) {
            const __bf16* lwb = (k & 1) ? lw1 : lw0;
            const int dy = k / KSZ, dx = k - dy * KSZ;

            bf16x8 bfr[4];
            #pragma unroll
            for (int nf = 0; nf < 4; ++nf) {
                int pix = (wvv * 4 + nf + dy) * TW + (px + dx);
                int row = pix >> 1;
                int off = row * 128 + (((((pix & 1) << 2) + g) ^ (row & 7)) << 4);
                bfr[nf] = *(const bf16x8*)((const char*)lx + off);
            }
            bf16x8 afr[MFT];
            #pragma unroll
            for (int m = 0; m < MFT; ++m) {
                int o = m * 16 + px;
                int row = o >> 1;
                int off = row * 128 + (((((o & 1) << 2) + g) ^ (row & 7)) << 4);
                afr[m] = *(const bf16x8*)((const char*)lwb + off);
            }
            __builtin_amdgcn_s_setprio(1);
            #pragma unroll
            for (int m = 0; m < MFT; ++m)
                #pragma unroll
                for (int nf = 0; nf < 4; ++nf)
                    acc[m][nf] = __builtin_amdgcn_mfma_f32_16x16x32_bf16(
                        afr[m], bfr[nf], acc[m][nf], 0, 0, 0);
            __builtin_amdgcn_s_setprio(0);

            if (k == KK - 1) break;

            asm volatile("s_waitcnt lgkmcnt(0)" ::: "memory");
            __builtin_amdgcn_sched_barrier(0);
            __builtin_amdgcn_s_barrier();    // all waves done with lw[k&1]
            bool issued = (k + 2 < KK);
            if (issued) STAGE(ci, k + 2, (k & 1) ? lw1 : lw0);
            if constexpr (MFT == 5) {
                if (issued && wvv < 3) asm volatile("s_waitcnt vmcnt(2)" ::: "memory");
                else                   asm volatile("s_waitcnt vmcnt(0)" ::: "memory");
            } else {
                if (issued) asm volatile("s_waitcnt vmcnt(1)" ::: "memory");
                else        asm volatile("s_waitcnt vmcnt(0)" ::: "memory");
            }
            __builtin_amdgcn_sched_barrier(0);
            __builtin_amdgcn_s_barrier();    // slice k+1 visible
        }
    }

    // ---- epilogue (D row = g*4+j (+16*m), col = px)
    #pragma unroll
    for (int m = 0; m < MFT; ++m) {
        #pragma unroll
        for (int nf = 0; nf < 4; ++nf) {
            int row = h0 + wvv * 4 + nf, col = w0 + px;
            if (m < 4) {
                float vj[4];
                #pragma unroll
                for (int j = 0; j < 4; ++j) {
                    float v = acc[m][nf][j] + lb[m * 16 + g * 4 + j];
                    if (RELU) v = v > 0.f ? v : 0.01f * v;
                    vj[j] = v;
                }
                if constexpr (EPI == 0) {
                    bf16x4 pk;
                    #pragma unroll
                    for (int j = 0; j < 4; ++j) pk[j] = (__bf16)vj[j];
                    *(bf16x4*)(outh + ((((size_t)b << 16) + row * 256 + col) << 6)
                                    + m * 16 + g * 4) = pk;
                } else {
                    #pragma unroll
                    for (int j = 0; j < 4; ++j)
                        outf[((size_t)(b * 64 + m * 16 + g * 4 + j) << 16)
                             + row * 256 + col] = vj[j];
                }
            } else {
                #pragma unroll
                for (int j = 0; j < 4; ++j) {
                    int o2 = g * 4 + j;
                    if (o2 < 9)
                        out2[((size_t)(b * 9 + o2) << 16) + row * 256 + col]
                            = acc[m][nf][j] + lb[64 + o2];
                }
            }
        }
    }
}

// 1x1 conv (residual) from NHWC bf16 x -> f32 NCHW.
__device__ void conv1x1_body(char* smem, int cb,
    const __bf16* __restrict__ xh, const float* __restrict__ w,
    const float* __restrict__ bias, float* __restrict__ out)
{
    float* lwT = (float*)smem;    // [i][o] 4096
    float* lb  = lwT + 4096;
    int t = threadIdx.x;
    for (int s = t; s < 4096; s += 256) lwT[s] = w[(s & 63) * 64 + (s >> 6)];
    if (t < 64) lb[t] = bias[t];
    __syncthreads();

    int p  = cb * 256 + t;
    int b  = p >> 16, hw = p & 65535;
    const __bf16* xp = xh + (size_t)p * 64;

    float acc[64];
    #pragma unroll
    for (int o = 0; o < 64; ++o) acc[o] = lb[o];

    #pragma unroll
    for (int c8 = 0; c8 < 8; ++c8) {
        bf16x8 v8 = *(const bf16x8*)(xp + c8 * 8);
        #pragma unroll
        for (int j = 0; j < 8; ++j) {
            float xi = (float)v8[j];
            const float4* w4 = (const float4*)&lwT[(c8 * 8 + j) * 64];
            #pragma unroll
            for (int o4 = 0; o4 < 16; ++o4) {
                float4 wv = w4[o4];
                acc[o4*4+0] += wv.x * xi;
                acc[o4*4+1] += wv.y * xi;
                acc[o4*4+2] += wv.z * xi;
                acc[o4*4+3] += wv.w * xi;
            }
        }
    }
    float* op = out + (((size_t)b * 64) << 16) + hw;
    #pragma unroll
    for (int o = 0; o < 64; ++o) op[(size_t)o << 16] = acc[o];
}

// ===========================================================================
// Super-kernels: plain __launch_bounds__(256) — NO min-waves bound (round-11
// lesson: the ",4" cap forced VGPR=64 and spilled the MFMA accumulators).
// ===========================================================================

// super1: F1 || c3_1, interleaved by bid parity. Grid 1024.
__global__ __launch_bounds__(256) void k_super1(
    const __bf16* mh, const __bf16* xh,
    const __bf16* wbF1, const __bf16* wbc1,
    const float* mt1_b, const float* aw1_b, const float* c1_b,
    __bf16* maska, float* wgt, __bf16* x1h)
{
    __shared__ __align__(16) char smem[38400];
    int bid = blockIdx.x;
    int sub = bid >> 1;
    if ((bid & 1) == 0) {
        mconv_body<5,5,1,0>(smem, sub & 15, (sub >> 4) & 15, sub >> 8,
                            mh, wbF1, mt1_b, aw1_b, nullptr, maska, wgt);
    } else {
        mconv_body<3,4,0,0>(smem, sub & 15, (sub >> 4) & 15, sub >> 8,
                            xh, wbc1, c1_b, nullptr, nullptr, x1h, nullptr);
    }
}

// super2: F2 || c3_2 || conv1x1, interleaved by bid%3. Grid 1536.
__global__ __launch_bounds__(256) void k_super2(
    const __bf16* maska, const __bf16* xah, const __bf16* xh,
    const __bf16* wbF2, const __bf16* wbc2,
    const float* mt2_b, const float* aw2_b, const float* c2_b,
    const float* crw, const float* crb,
    float* outm, float* wgt, __bf16* x2h, float* outx)
{
    __shared__ __align__(16) char smem[38400];
    int bid  = blockIdx.x;
    int sub  = bid / 3;
    int role = bid - sub * 3;
    if (role == 0) {
        mconv_body<5,5,1,1>(smem, sub & 15, (sub >> 4) & 15, sub >> 8,
                            maska, wbF2, mt2_b, aw2_b, outm, nullptr, wgt);
    } else if (role == 1) {
        mconv_body<3,4,0,0>(smem, sub & 15, (sub >> 4) & 15, sub >> 8,
                            xah, wbc2, c2_b, nullptr, nullptr, x2h, nullptr);
    } else {
        conv1x1_body(smem, sub, xh, crw, crb, outx);
    }
}

// ---------------------------------------------------------------------------
// Adaptive einsum, coalesced: 8 threads/pixel. -> bf16 NHWC.
// ---------------------------------------------------------------------------
__global__ __launch_bounds__(256, 4) void k_ada1(
    const float* __restrict__ wgt, const __bf16* __restrict__ xin,
    __bf16* __restrict__ outh)
{
    int t  = threadIdx.x;
    int pg = t >> 3, c8 = t & 7;
    int p  = blockIdx.x * 32 + pg;
    int b  = p >> 16, hw = p & 65535;
    int h  = hw >> 8, wc = hw & 255;

    const float* wp = wgt + ((size_t)(b * 9) << 16) + hw;
    const __bf16* cen = xin + (size_t)p * 64 + c8 * 8;

    float wk[9];
    const __bf16* nbp[9];
    #pragma unroll
    for (int dy = 0; dy < 3; ++dy)
        #pragma unroll
        for (int dx = 0; dx < 3; ++dx) {
            int k = dy * 3 + dx;
            bool ok = ((unsigned)(h + dy - 1) < 256u) &&
                      ((unsigned)(wc + dx - 1) < 256u);
            wk[k]  = ok ? wp[(size_t)k << 16] : 0.f;
            nbp[k] = ok ? cen + ((dy - 1) * 256 + (dx - 1)) * 64 : cen;
        }

    float acc[8] = {0.f,0.f,0.f,0.f,0.f,0.f,0.f,0.f};
    #pragma unroll
    for (int k = 0; k < 9; ++k) {
        bf16x8 v8 = *(const bf16x8*)nbp[k];
        float w = wk[k];
        #pragma unroll
        for (int j = 0; j < 8; ++j) acc[j] += w * (float)v8[j];
    }

    bf16x8 o8;
    #pragma unroll
    for (int j = 0; j < 8; ++j) {
        float v = acc[j];
        o8[j] = (__bf16)(v > 0.f ? v : 0.01f * v);
    }
    *(bf16x8*)(outh + (size_t)p * 64 + c8 * 8) = o8;
}

// ---------------------------------------------------------------------------
// Final adaptive einsum + RMW residual add (f32 NCHW via LDS transpose).
// ---------------------------------------------------------------------------
__global__ __launch_bounds__(256, 4) void k_ada2(
    const float* __restrict__ wgt, const __bf16* __restrict__ x2h,
    float* __restrict__ outf)
{
    __shared__ float ls[32 * 65];

    int t  = threadIdx.x;
    int pg = t >> 3, c8 = t & 7;
    int p  = blockIdx.x * 32 + pg;
    int b  = p >> 16, hw = p & 65535;
    int h  = hw >> 8, wc = hw & 255;

    const float* wp = wgt + ((size_t)(b * 9) << 16) + hw;
    const __bf16* cen = x2h + (size_t)p * 64 + c8 * 8;

    float wk[9];
    const __bf16* nbp[9];
    #pragma unroll
    for (int dy = 0; dy < 3; ++dy)
        #pragma unroll
        for (int dx = 0; dx < 3; ++dx) {
            int k = dy * 3 + dx;
            bool ok = ((unsigned)(h + dy - 1) < 256u) &&
                      ((unsigned)(wc + dx - 1) < 256u);
            wk[k]  = ok ? wp[(size_t)k << 16] : 0.f;
            nbp[k] = ok ? cen + ((dy - 1) * 256 + (dx - 1)) * 64 : cen;
        }

    float acc[8] = {0.f,0.f,0.f,0.f,0.f,0.f,0.f,0.f};
    #pragma unroll
    for (int k = 0; k < 9; ++k) {
        bf16x8 v8 = *(const bf16x8*)nbp[k];
        float w = wk[k];
        #pragma unroll
        for (int j = 0; j < 8; ++j) acc[j] += w * (float)v8[j];
    }

    #pragma unroll
    for (int j = 0; j < 8; ++j) {
        float v = acc[j];
        ls[pg * 65 + c8 * 8 + j] = v > 0.f ? v : 0.01f * v;
    }
    __syncthreads();

    int pbase = blockIdx.x * 32;
    int bb    = pbase >> 16, hwb = pbase & 65535;
    int pix   = t & 31, cq = t >> 5;
    #pragma unroll
    for (int i = 0; i < 8; ++i) {
        int c = i * 8 + cq;
        float v = ls[pix * 65 + c];
        float* op = outf + ((size_t)(bb * 64 + c) << 16) + hwb + pix;
        *op = *op + v;
    }
}

// ---------------------------------------------------------------------------
// Buffer plan (ws use = 72,589,312 B; ws_size ~256 MiB per fillBuffer trace):
//   wgt   f32  @0           4,718,592   adaptive weights (F1->ada1, F2->ada2)
//   xh    bf16 @4,718,592  16,777,216   x NHWC (live whole call)
//   mh    bf16 @21,495,808 16,777,216   mask NHWC; x2h reuses after F1
//   wb    bf16 @38,273,024    761,856   prepped conv weights (ci-split)
//   maska bf16 @39,034,880 16,777,216   F1 out / F2 in  (ws: no d_out races)
//   xah   bf16 @55,812,096 16,777,216   ada1 out / c3_2 in
//   x1h   = out_m scratch (c3_1 out, ada1 in; F2 writes final out_m later)
// Launches: prep -> super1(F1||c3_1) -> ada1 -> super2(F2||c3_2||1x1) -> ada2
// ---------------------------------------------------------------------------
extern "C" void kernel_launch(void* const* d_in, const int* in_sizes, int n_in,
                              void* d_out, int out_size, void* d_ws, size_t ws_size,
                              hipStream_t stream)
{
    const float* x     = (const float*)d_in[0];
    const float* mask  = (const float*)d_in[1];
    const float* aw1_w = (const float*)d_in[2];
    const float* aw1_b = (const float*)d_in[3];
    const float* mt1_w = (const float*)d_in[4];
    const float* mt1_b = (const float*)d_in[5];
    const float* c1_w  = (const float*)d_in[6];
    const float* c1_b  = (const float*)d_in[7];
    const float* aw2_w = (const float*)d_in[8];
    const float* aw2_b = (const float*)d_in[9];
    const float* mt2_w = (const float*)d_in[10];
    const float* mt2_b = (const float*)d_in[11];
    const float* c2_w  = (const float*)d_in[12];
    const float* c2_b  = (const float*)d_in[13];
    const float* cr_w  = (const float*)d_in[14];
    const float* cr_b  = (const float*)d_in[15];

    float* out_x = (float*)d_out;
    float* out_m = (float*)d_out + 8388608;

    float*  wgt   = (float*)d_ws;
    __bf16* xh    = (__bf16*)((char*)d_ws + 4718592);
    __bf16* mh    = (__bf16*)((char*)d_ws + 21495808);
    __bf16* x2h   = mh;                                // sequential live ranges
    __bf16* wbase = (__bf16*)((char*)d_ws + 38273024);
    __bf16* wb_c1 = wbase;             // 36864 elems
    __bf16* wb_c2 = wbase + 36864;     // 36864
    __bf16* wb_F1 = wbase + 73728;     // 153600
    __bf16* wb_F2 = wbase + 227328;    // 153600
    __bf16* maska = (__bf16*)((char*)d_ws + 39034880);
    __bf16* xah   = (__bf16*)((char*)d_ws + 55812096);
    __bf16* x1h   = (__bf16*)out_m;                    // scratch until F2

    dim3 blk(256);

    // 1. merged prep
    k_prep<<<dim3(2512), blk, 0, stream>>>(x, mask, c1_w, c2_w,
        mt1_w, aw1_w, mt2_w, aw2_w, xh, mh, wb_c1, wb_c2, wb_F1, wb_F2);

    // 2. super1: F1(mh)->maska,wgt || c3_1(xh)->x1h
    k_super1<<<dim3(1024), blk, 0, stream>>>(mh, xh, wb_F1, wb_c1,
        mt1_b, aw1_b, c1_b, maska, wgt, x1h);

    // 3. xa = lrelu(ada(wgt, x1)) -> xah
    k_ada1<<<dim3(4096), blk, 0, stream>>>(wgt, x1h, xah);

    // 4. super2: F2(maska)->out_m,wgt || c3_2(xah)->x2h || conv1x1(xh)->out_x
    k_super2<<<dim3(1536), blk, 0, stream>>>(maska, xah, xh, wb_F2, wb_c2,
        mt2_b, aw2_b, c2_b, cr_w, cr_b, out_m, wgt, x2h, out_x);

    // 5. out_x += lrelu(ada(wgt, x2))
    k_ada2<<<dim3(4096), blk, 0, stream>>>(wgt, x2h, out_x);
}

// Round 15
// 186.331 us; speedup vs baseline: 1.4228x; 1.4228x over previous
//
#include <hip/hip_runtime.h>

#define HWSZ 65536   // 256*256
#define CCH  64

typedef __bf16 bf16x8 __attribute__((ext_vector_type(8)));
typedef __bf16 bf16x4 __attribute__((ext_vector_type(4)));
typedef float  f32x4  __attribute__((ext_vector_type(4)));

__device__ inline void gload_lds16(const void* g, void* l) {
    __builtin_amdgcn_global_load_lds(
        (const __attribute__((address_space(1))) void*)g,
        (__attribute__((address_space(3))) void*)l, 16, 0, 0);
}

// ===========================================================================
// Prep bodies (one launch). W layouts: ci-split + 2-rows-per-128B packed +
// inverse-swizzled (linear global_load_lds + XOR-swizzled read).
// ===========================================================================

__device__ void cvt_body(int cb, const float* __restrict__ src,
                         __bf16* __restrict__ dst)
{
    int p  = cb * 256 + threadIdx.x;
    int b  = p >> 16, hw = p & 65535;
    const float* sp = src + (((size_t)b * 64) << 16) + hw;
    __bf16* dp = dst + (size_t)p * 64;
    #pragma unroll
    for (int c8 = 0; c8 < 8; ++c8) {
        bf16x8 v8;
        #pragma unroll
        for (int j = 0; j < 8; ++j)
            v8[j] = (__bf16)sp[(size_t)(c8 * 8 + j) << 16];
        *(bf16x8*)(dp + c8 * 8) = v8;
    }
}

__device__ void prep3_body(int cb, const float* __restrict__ src,
                           __bf16* __restrict__ dst)
{
    int t = cb * 256 + threadIdx.x;
    if (t >= 2 * 9 * 2048) return;
    int j  = t & 7;
    int u  = (t >> 3) & 255;
    int q  = t >> 11;
    int k  = q % 9, ci = q / 9;
    int r  = u >> 3;
    int v  = (u & 7) ^ (r & 7);
    int o  = 2 * r + (v >> 2);
    int g  = v & 3;
    int i  = ci * 32 + g * 8 + j;
    dst[t] = (__bf16)src[((size_t)o * 64 + i) * 9 + k];
}

__device__ void prepF_body(int cb, const float* __restrict__ mt,
                           const float* __restrict__ aw, __bf16* __restrict__ dst)
{
    int t = cb * 256 + threadIdx.x;
    if (t >= 2 * 25 * 3072) return;
    int j  = t & 7;
    int u  = (t >> 3) % 384;
    int q  = t / 3072;
    int k  = q % 25, ci = q / 25;
    int r  = u >> 3;
    int v  = (u & 7) ^ (r & 7);
    int o  = 2 * r + (v >> 2);
    int g  = v & 3;
    int i  = ci * 32 + g * 8 + j;
    float val = 0.f;
    if (o < 64)      val = mt[((size_t)o * 64 + i) * 25 + k];
    else if (o < 73) val = aw[((size_t)(o - 64) * 64 + i) * 25 + k];
    dst[t] = (__bf16)val;
}

// residual 1x1 conv from ORIGINAL f32 x (L3-hot alongside cvt) -> bf16 NCHW.
// thread = pixel: weights wave-uniform (LDS broadcast float4), coalesced IO.
__device__ void conv1x1p_body(float* lwT, float* lb, int cb,
    const float* __restrict__ x, const float* __restrict__ w,
    const float* __restrict__ bias, __bf16* __restrict__ res)
{
    int t = threadIdx.x;
    for (int s = t; s < 4096; s += 256) lwT[s] = w[(s & 63) * 64 + (s >> 6)];
    if (t < 64) lb[t] = bias[t];
    __syncthreads();

    int p  = cb * 256 + t;
    int b  = p >> 16, hw = p & 65535;
    const float* xp = x + (((size_t)b * 64) << 16) + hw;

    float acc[64];
    #pragma unroll
    for (int o = 0; o < 64; ++o) acc[o] = lb[o];

    #pragma unroll 4
    for (int i = 0; i < 64; ++i) {
        float xi = xp[(size_t)i << 16];
        const float4* w4 = (const float4*)&lwT[i * 64];
        #pragma unroll
        for (int o4 = 0; o4 < 16; ++o4) {
            float4 wv = w4[o4];
            acc[o4*4+0] += wv.x * xi;
            acc[o4*4+1] += wv.y * xi;
            acc[o4*4+2] += wv.z * xi;
            acc[o4*4+3] += wv.w * xi;
        }
    }
    __bf16* op = res + (((size_t)b * 64) << 16) + hw;
    #pragma unroll
    for (int o = 0; o < 64; ++o) op[(size_t)o << 16] = (__bf16)acc[o];
}

// prep super-kernel. Grid 3024.
__global__ __launch_bounds__(256) void k_prep(
    const float* x, const float* mask,
    const float* c1w, const float* c2w,
    const float* mt1w, const float* aw1w,
    const float* mt2w, const float* aw2w,
    const float* crw, const float* crb,
    __bf16* xh, __bf16* mh, __bf16* resh,
    __bf16* wbc1, __bf16* wbc2, __bf16* wbF1, __bf16* wbF2)
{
    __shared__ __align__(16) float s1x1[4160];
    int bid = blockIdx.x;
    if      (bid < 512)  conv1x1p_body(s1x1, s1x1 + 4096, bid, x, crw, crb, resh);
    else if (bid < 1024) cvt_body(bid - 512, x, xh);
    else if (bid < 1536) cvt_body(bid - 1024, mask, mh);
    else if (bid < 1680) prep3_body(bid - 1536, c1w, wbc1);
    else if (bid < 1824) prep3_body(bid - 1680, c2w, wbc2);
    else if (bid < 2424) prepF_body(bid - 1824, mt1w, aw1w, wbF1);
    else                 prepF_body(bid - 2424, mt2w, aw2w, wbF2);
}

// ---------------------------------------------------------------------------
// Fused 5x5 MFMA conv (mt 64ch + aw 9ch), ci-split, W double-buffered via
// async global_load_lds + counted vmcnt (r13-proven). EPI=0: bf16 NHWC out;
// EPI=1: f32 NCHW out. aw -> out2 f32 NCHW.
// ---------------------------------------------------------------------------
template<int EPI>
__global__ __launch_bounds__(256) void k_conv5(
    const __bf16* __restrict__ xh, const __bf16* __restrict__ wb,
    const float* __restrict__ bias, const float* __restrict__ bias2,
    float* __restrict__ outf, __bf16* __restrict__ outh,
    float* __restrict__ out2)
{
    constexpr int TW    = 20;
    constexpr int NPIX  = 400;
    constexpr int KK    = 25;
    constexpr int SROWS = 96;
    constexpr int SLICE = SROWS * 64;
    constexpr int NPIX2 = NPIX / 2;
    constexpr int MFT   = 5;

    __shared__ __align__(16) __bf16 lx[NPIX2 * 64];
    __shared__ __align__(16) __bf16 lw[2][SROWS * 32];
    __shared__ float lb[80];

    const int t    = threadIdx.x;
    const int w0   = blockIdx.x * 16, h0 = blockIdx.y * 16, b = blockIdx.z;
    const int wvv  = t >> 6;
    const int lane = t & 63;
    const int px   = lane & 15;
    const int g    = lane >> 4;

    auto STAGE = [&](int ci, int k, int buf) {
        const char* gs = (const char*)wb + (size_t)(ci * KK + k) * SLICE;
        if (wvv < 3) {
            #pragma unroll
            for (int r = 0; r < 2; ++r) {
                int ub = wvv * 128 + r * 64;
                gload_lds16(gs + (ub + lane) * 16, (char*)lw[buf] + ub * 16);
            }
        }
    };

    f32x4 acc[MFT][4];
    #pragma unroll
    for (int m = 0; m < MFT; ++m)
        #pragma unroll
        for (int nf = 0; nf < 4; ++nf)
            acc[m][nf] = (f32x4){0.f, 0.f, 0.f, 0.f};

    bf16x8 zv;
    #pragma unroll
    for (int j = 0; j < 8; ++j) zv[j] = (__bf16)0.f;

    for (int ci = 0; ci < 2; ++ci) {
        if (ci) __syncthreads();
        STAGE(ci, 0, 0);
        STAGE(ci, 1, 1);
        if (ci == 0) {
            if (t < 64) lb[t] = bias[t];
            if (t >= 64 && t < 80) lb[t] = (t - 64 < 9) ? bias2[t - 64] : 0.f;
        }

        #pragma unroll
        for (int xi = 0; xi < 7; ++xi) {
            int e = xi * 256 + t;
            if (e < NPIX * 4) {
                int pix = e >> 2, c4 = e & 3;
                int sy = pix / TW, sx = pix - sy * TW;
                int gy = h0 + sy - 2, gx = w0 + sx - 2;
                bool ok = (unsigned)gy < 256u && (unsigned)gx < 256u;
                bf16x8 v8 = zv;
                if (ok) v8 = *(const bf16x8*)(xh + ((((size_t)b << 16) + gy * 256 + gx) << 6)
                                              + ci * 32 + c4 * 8);
                int row = pix >> 1;
                int off = row * 128 + (((((pix & 1) << 2) + c4) ^ (row & 7)) << 4);
                *(bf16x8*)((char*)lx + off) = v8;
            }
        }
        __syncthreads();

        #pragma unroll
        for (int k = 0; k < KK; ++k) {
            const __bf16* lwb = (k & 1) ? lw[1] : lw[0];
            const int dy = k / 5, dx = k - dy * 5;

            bf16x8 bfr[4];
            #pragma unroll
            for (int nf = 0; nf < 4; ++nf) {
                int pix = (wvv * 4 + nf + dy) * TW + (px + dx);
                int row = pix >> 1;
                int off = row * 128 + (((((pix & 1) << 2) + g) ^ (row & 7)) << 4);
                bfr[nf] = *(const bf16x8*)((const char*)lx + off);
            }
            bf16x8 afr[MFT];
            #pragma unroll
            for (int m = 0; m < MFT; ++m) {
                int o = m * 16 + px;
                int row = o >> 1;
                int off = row * 128 + (((((o & 1) << 2) + g) ^ (row & 7)) << 4);
                afr[m] = *(const bf16x8*)((const char*)lwb + off);
            }
            __builtin_amdgcn_s_setprio(1);
            #pragma unroll
            for (int m = 0; m < MFT; ++m)
                #pragma unroll
                for (int nf = 0; nf < 4; ++nf)
                    acc[m][nf] = __builtin_amdgcn_mfma_f32_16x16x32_bf16(
                        afr[m], bfr[nf], acc[m][nf], 0, 0, 0);
            __builtin_amdgcn_s_setprio(0);

            if (k == KK - 1) break;

            asm volatile("s_waitcnt lgkmcnt(0)" ::: "memory");
            __builtin_amdgcn_sched_barrier(0);
            __builtin_amdgcn_s_barrier();
            bool issued = (k + 2 < KK);
            if (issued) STAGE(ci, k + 2, k & 1);
            if (issued && wvv < 3) asm volatile("s_waitcnt vmcnt(2)" ::: "memory");
            else                   asm volatile("s_waitcnt vmcnt(0)" ::: "memory");
            __builtin_amdgcn_sched_barrier(0);
            __builtin_amdgcn_s_barrier();
        }
    }

    // epilogue: D row = g*4+j (+16*m), col = px
    #pragma unroll
    for (int m = 0; m < MFT; ++m) {
        #pragma unroll
        for (int nf = 0; nf < 4; ++nf) {
            int row = h0 + wvv * 4 + nf, col = w0 + px;
            if (m < 4) {
                float vj[4];
                #pragma unroll
                for (int j = 0; j < 4; ++j) {
                    float v = acc[m][nf][j] + lb[m * 16 + g * 4 + j];
                    vj[j] = v > 0.f ? v : 0.01f * v;   // mt path always lrelu
                }
                if constexpr (EPI == 0) {
                    bf16x4 pk;
                    #pragma unroll
                    for (int j = 0; j < 4; ++j) pk[j] = (__bf16)vj[j];
                    *(bf16x4*)(outh + ((((size_t)b << 16) + row * 256 + col) << 6)
                                    + m * 16 + g * 4) = pk;
                } else {
                    #pragma unroll
                    for (int j = 0; j < 4; ++j)
                        outf[((size_t)(b * 64 + m * 16 + g * 4 + j) << 16)
                             + row * 256 + col] = vj[j];
                }
            } else {
                #pragma unroll
                for (int j = 0; j < 4; ++j) {
                    int o2 = g * 4 + j;
                    if (o2 < 9)
                        out2[((size_t)(b * 9 + o2) << 16) + row * 256 + col]
                            = acc[m][nf][j] + lb[64 + o2];
                }
            }
        }
    }
}

// ---------------------------------------------------------------------------
// 3x3 MFMA conv, ci-split, ALL 9 W slices staged per ci-phase (36.9KB) ->
// zero barriers inside the 9-step k-loop (one schedulable region of
// 72 ds_reads + 144 MFMA). LDS total 57.9KB -> 2 blocks/CU. bf16 NHWC out.
// ---------------------------------------------------------------------------
__global__ __launch_bounds__(256) void k_conv3(
    const __bf16* __restrict__ xh, const __bf16* __restrict__ wb,
    const float* __restrict__ bias, __bf16* __restrict__ outh)
{
    constexpr int TW    = 18;
    constexpr int NPIX  = 324;
    constexpr int NPIX2 = 162;

    __shared__ __align__(16) __bf16 lx[NPIX2 * 64];   // 20736 B
    __shared__ __align__(16) __bf16 lw[9 * 2048];     // 36864 B
    __shared__ float lb[64];

    const int t    = threadIdx.x;
    const int w0   = blockIdx.x * 16, h0 = blockIdx.y * 16, b = blockIdx.z;
    const int wvv  = t >> 6;
    const int lane = t & 63;
    const int px   = lane & 15;
    const int g    = lane >> 4;

    f32x4 acc[4][4];
    #pragma unroll
    for (int m = 0; m < 4; ++m)
        #pragma unroll
        for (int nf = 0; nf < 4; ++nf)
            acc[m][nf] = (f32x4){0.f, 0.f, 0.f, 0.f};

    bf16x8 zv;
    #pragma unroll
    for (int j = 0; j < 8; ++j) zv[j] = (__bf16)0.f;

    for (int ci = 0; ci < 2; ++ci) {
        if (ci) __syncthreads();             // prev phase's readers done
        // stage ALL 9 W slices for this ci (9 x 4KB, linear async)
        {
            const char* gs = (const char*)wb + (size_t)ci * 9 * 4096;
            #pragma unroll
            for (int r = 0; r < 9; ++r) {
                int ub = r * 256 + wvv * 64;          // 16B-unit index
                gload_lds16(gs + (ub + lane) * 16, (char*)lw + ub * 16);
            }
        }
        if (ci == 0 && t < 64) lb[t] = bias[t];

        // stage x half-channels (2-pixel-packed swizzled rows)
        #pragma unroll
        for (int xi = 0; xi < 6; ++xi) {
            int e = xi * 256 + t;
            if (e < NPIX * 4) {
                int pix = e >> 2, c4 = e & 3;
                int sy = pix / TW, sx = pix - sy * TW;
                int gy = h0 + sy - 1, gx = w0 + sx - 1;
                bool ok = (unsigned)gy < 256u && (unsigned)gx < 256u;
                bf16x8 v8 = zv;
                if (ok) v8 = *(const bf16x8*)(xh + ((((size_t)b << 16) + gy * 256 + gx) << 6)
                                              + ci * 32 + c4 * 8);
                int row = pix >> 1;
                int off = row * 128 + (((((pix & 1) << 2) + c4) ^ (row & 7)) << 4);
                *(bf16x8*)((char*)lx + off) = v8;
            }
        }
        __syncthreads();                     // drains vmcnt+lgkm: lw, lx ready

        // 9 k-steps, NO barriers: one big scheduling region
        #pragma unroll
        for (int k = 0; k < 9; ++k) {
            const __bf16* lwb = lw + k * 2048;
            const int dy = k / 3, dx = k - dy * 3;

            bf16x8 bfr[4];
            #pragma unroll
            for (int nf = 0; nf < 4; ++nf) {
                int pix = (wvv * 4 + nf + dy) * TW + (px + dx);
                int row = pix >> 1;
                int off = row * 128 + (((((pix & 1) << 2) + g) ^ (row & 7)) << 4);
                bfr[nf] = *(const bf16x8*)((const char*)lx + off);
            }
            bf16x8 afr[4];
            #pragma unroll
            for (int m = 0; m < 4; ++m) {
                int o = m * 16 + px;
                int row = o >> 1;
                int off = row * 128 + (((((o & 1) << 2) + g) ^ (row & 7)) << 4);
                afr[m] = *(const bf16x8*)((const char*)lwb + off);
            }
            __builtin_amdgcn_s_setprio(1);
            #pragma unroll
            for (int m = 0; m < 4; ++m)
                #pragma unroll
                for (int nf = 0; nf < 4; ++nf)
                    acc[m][nf] = __builtin_amdgcn_mfma_f32_16x16x32_bf16(
                        afr[m], bfr[nf], acc[m][nf], 0, 0, 0);
            __builtin_amdgcn_s_setprio(0);
        }
    }

    // epilogue: bf16 NHWC
    #pragma unroll
    for (int m = 0; m < 4; ++m) {
        #pragma unroll
        for (int nf = 0; nf < 4; ++nf) {
            int row = h0 + wvv * 4 + nf, col = w0 + px;
            bf16x4 pk;
            #pragma unroll
            for (int j = 0; j < 4; ++j) {
                float v = acc[m][nf][j] + lb[m * 16 + g * 4 + j];
                pk[j] = (__bf16)v;          // no relu on c-convs
            }
            *(bf16x4*)(outh + ((((size_t)b << 16) + row * 256 + col) << 6)
                            + m * 16 + g * 4) = pk;
        }
    }
}

// ---------------------------------------------------------------------------
// Adaptive einsum, coalesced: 8 threads/pixel. -> bf16 NHWC.
// ---------------------------------------------------------------------------
__global__ __launch_bounds__(256, 4) void k_ada1(
    const float* __restrict__ wgt, const __bf16* __restrict__ xin,
    __bf16* __restrict__ outh)
{
    int t  = threadIdx.x;
    int pg = t >> 3, c8 = t & 7;
    int p  = blockIdx.x * 32 + pg;
    int b  = p >> 16, hw = p & 65535;
    int h  = hw >> 8, wc = hw & 255;

    const float* wp = wgt + ((size_t)(b * 9) << 16) + hw;
    const __bf16* cen = xin + (size_t)p * 64 + c8 * 8;

    float wk[9];
    const __bf16* nbp[9];
    #pragma unroll
    for (int dy = 0; dy < 3; ++dy)
        #pragma unroll
        for (int dx = 0; dx < 3; ++dx) {
            int k = dy * 3 + dx;
            bool ok = ((unsigned)(h + dy - 1) < 256u) &&
                      ((unsigned)(wc + dx - 1) < 256u);
            wk[k]  = ok ? wp[(size_t)k << 16] : 0.f;
            nbp[k] = ok ? cen + ((dy - 1) * 256 + (dx - 1)) * 64 : cen;
        }

    float acc[8] = {0.f,0.f,0.f,0.f,0.f,0.f,0.f,0.f};
    #pragma unroll
    for (int k = 0; k < 9; ++k) {
        bf16x8 v8 = *(const bf16x8*)nbp[k];
        float w = wk[k];
        #pragma unroll
        for (int j = 0; j < 8; ++j) acc[j] += w * (float)v8[j];
    }

    bf16x8 o8;
    #pragma unroll
    for (int j = 0; j < 8; ++j) {
        float v = acc[j];
        o8[j] = (__bf16)(v > 0.f ? v : 0.01f * v);
    }
    *(bf16x8*)(outh + (size_t)p * 64 + c8 * 8) = o8;
}

// ---------------------------------------------------------------------------
// Final adaptive einsum + residual add from bf16 res (PURE WRITE to out_x,
// f32 NCHW via LDS transpose; the 33.5MB RMW read is gone).
// ---------------------------------------------------------------------------
__global__ __launch_bounds__(256, 4) void k_ada2(
    const float* __restrict__ wgt, const __bf16* __restrict__ x2h,
    const __bf16* __restrict__ resh, float* __restrict__ outf)
{
    __shared__ float ls[32 * 65];

    int t  = threadIdx.x;
    int pg = t >> 3, c8 = t & 7;
    int p  = blockIdx.x * 32 + pg;
    int b  = p >> 16, hw = p & 65535;
    int h  = hw >> 8, wc = hw & 255;

    const float* wp = wgt + ((size_t)(b * 9) << 16) + hw;
    const __bf16* cen = x2h + (size_t)p * 64 + c8 * 8;

    float wk[9];
    const __bf16* nbp[9];
    #pragma unroll
    for (int dy = 0; dy < 3; ++dy)
        #pragma unroll
        for (int dx = 0; dx < 3; ++dx) {
            int k = dy * 3 + dx;
            bool ok = ((unsigned)(h + dy - 1) < 256u) &&
                      ((unsigned)(wc + dx - 1) < 256u);
            wk[k]  = ok ? wp[(size_t)k << 16] : 0.f;
            nbp[k] = ok ? cen + ((dy - 1) * 256 + (dx - 1)) * 64 : cen;
        }

    float acc[8] = {0.f,0.f,0.f,0.f,0.f,0.f,0.f,0.f};
    #pragma unroll
    for (int k = 0; k < 9; ++k) {
        bf16x8 v8 = *(const bf16x8*)nbp[k];
        float w = wk[k];
        #pragma unroll
        for (int j = 0; j < 8; ++j) acc[j] += w * (float)v8[j];
    }

    #pragma unroll
    for (int j = 0; j < 8; ++j) {
        float v = acc[j];
        ls[pg * 65 + c8 * 8 + j] = v > 0.f ? v : 0.01f * v;
    }
    __syncthreads();

    int pbase = blockIdx.x * 32;
    int bb    = pbase >> 16, hwb = pbase & 65535;
    int pix   = t & 31, cq = t >> 5;
    #pragma unroll
    for (int i = 0; i < 8; ++i) {
        int c = i * 8 + cq;
        size_t oi = ((size_t)(bb * 64 + c) << 16) + hwb + pix;
        outf[oi] = ls[pix * 65 + c] + (float)resh[oi];
    }
}

// ---------------------------------------------------------------------------
// Buffer plan (ws use = 55.8 MB; ws_size ~256 MiB):
//   wgt   f32  @0           4,718,592   adaptive weights (F1->ada1, F2->ada2)
//   xh    bf16 @4,718,592  16,777,216   x NHWC
//   mh    bf16 @21,495,808 16,777,216   mask NHWC; x2h reuses after F1
//   wb    bf16 @38,273,024    761,856   prepped conv weights (ci-split)
//   resh  bf16 @39,034,880 16,777,216   residual, bf16 NCHW (prep -> ada2)
// d_out scratch: out_x lower = maska_h, out_x upper = xa_h, out_m = x1_h.
// Launches: prep(+1x1) -> F1 -> c3_1 -> ada1 -> F2 -> c3_2 -> ada2.
// ---------------------------------------------------------------------------
extern "C" void kernel_launch(void* const* d_in, const int* in_sizes, int n_in,
                              void* d_out, int out_size, void* d_ws, size_t ws_size,
                              hipStream_t stream)
{
    const float* x     = (const float*)d_in[0];
    const float* mask  = (const float*)d_in[1];
    const float* aw1_w = (const float*)d_in[2];
    const float* aw1_b = (const float*)d_in[3];
    const float* mt1_w = (const float*)d_in[4];
    const float* mt1_b = (const float*)d_in[5];
    const float* c1_w  = (const float*)d_in[6];
    const float* c1_b  = (const float*)d_in[7];
    const float* aw2_w = (const float*)d_in[8];
    const float* aw2_b = (const float*)d_in[9];
    const float* mt2_w = (const float*)d_in[10];
    const float* mt2_b = (const float*)d_in[11];
    const float* c2_w  = (const float*)d_in[12];
    const float* c2_b  = (const float*)d_in[13];
    const float* cr_w  = (const float*)d_in[14];
    const float* cr_b  = (const float*)d_in[15];

    float* out_x = (float*)d_out;
    float* out_m = (float*)d_out + 8388608;

    float*  wgt   = (float*)d_ws;
    __bf16* xh    = (__bf16*)((char*)d_ws + 4718592);
    __bf16* mh    = (__bf16*)((char*)d_ws + 21495808);
    __bf16* x2h   = mh;                                // sequential live ranges
    __bf16* wbase = (__bf16*)((char*)d_ws + 38273024);
    __bf16* wb_c1 = wbase;             // 36864 elems
    __bf16* wb_c2 = wbase + 36864;     // 36864
    __bf16* wb_F1 = wbase + 73728;     // 153600
    __bf16* wb_F2 = wbase + 227328;    // 153600
    __bf16* resh  = (__bf16*)((char*)d_ws + 39034880);

    __bf16* maska_h = (__bf16*)out_x;               // lower 16.78 MB
    __bf16* xa_h    = (__bf16*)out_x + 8388608;     // upper 16.78 MB
    __bf16* x1_h    = (__bf16*)out_m;               // lower 16.78 MB

    dim3 blk(256);
    dim3 gconv(16, 16, 2);
    dim3 gada(4096);

    // 0. merged prep: 1x1 residual + layout conversions + weight preps
    k_prep<<<dim3(3024), blk, 0, stream>>>(x, mask, c1_w, c2_w,
        mt1_w, aw1_w, mt2_w, aw2_w, cr_w, cr_b,
        xh, mh, resh, wb_c1, wb_c2, wb_F1, wb_F2);

    // 1. F1(mh): maska = lrelu(mt1) -> maska_h (bf16), weight1 = aw1 -> wgt
    k_conv5<0><<<gconv, blk, 0, stream>>>(mh, wb_F1, mt1_b, aw1_b,
                                          nullptr, maska_h, wgt);
    // 2. x1 = conv3x3(xh, c1) -> x1_h
    k_conv3<<<gconv, blk, 0, stream>>>(xh, wb_c1, c1_b, x1_h);
    // 3. xa = lrelu(ada(wgt, x1)) -> xa_h
    k_ada1<<<gada, blk, 0, stream>>>(wgt, x1_h, xa_h);
    // 4. F2(maska_h): final mask = lrelu(mt2) -> out_m (f32), weight2 -> wgt
    k_conv5<1><<<gconv, blk, 0, stream>>>(maska_h, wb_F2, mt2_b, aw2_b,
                                          out_m, nullptr, wgt);
    // 5. x2 = conv3x3(xa_h, c2) -> x2h
    k_conv3<<<gconv, blk, 0, stream>>>(xa_h, wb_c2, c2_b, x2h);
    // 6. out_x = lrelu(ada(wgt, x2)) + res   (pure write)
    k_ada2<<<gada, blk, 0, stream>>>(wgt, x2h, resh, out_x);
}

// Round 16
// 169.318 us; speedup vs baseline: 1.5658x; 1.1005x over previous
//
#include <hip/hip_runtime.h>

#define HWSZ 65536   // 256*256
#define CCH  64

typedef __bf16 bf16x8 __attribute__((ext_vector_type(8)));
typedef __bf16 bf16x4 __attribute__((ext_vector_type(4)));
typedef float  f32x4  __attribute__((ext_vector_type(4)));

__device__ inline void gload_lds16(const void* g, void* l) {
    __builtin_amdgcn_global_load_lds(
        (const __attribute__((address_space(1))) void*)g,
        (__attribute__((address_space(3))) void*)l, 16, 0, 0);
}

// ===========================================================================
// Prep bodies (one launch). W layouts: ci-split + 2-rows-per-128B packed +
// inverse-swizzled (linear global_load_lds + XOR-swizzled read).
// ===========================================================================

__device__ void cvt_body(int cb, const float* __restrict__ src,
                         __bf16* __restrict__ dst)
{
    int p  = cb * 256 + threadIdx.x;
    int b  = p >> 16, hw = p & 65535;
    const float* sp = src + (((size_t)b * 64) << 16) + hw;
    __bf16* dp = dst + (size_t)p * 64;
    #pragma unroll
    for (int c8 = 0; c8 < 8; ++c8) {
        bf16x8 v8;
        #pragma unroll
        for (int j = 0; j < 8; ++j)
            v8[j] = (__bf16)sp[(size_t)(c8 * 8 + j) << 16];
        *(bf16x8*)(dp + c8 * 8) = v8;
    }
}

__device__ void prep3_body(int cb, const float* __restrict__ src,
                           __bf16* __restrict__ dst)
{
    int t = cb * 256 + threadIdx.x;
    if (t >= 2 * 9 * 2048) return;
    int j  = t & 7;
    int u  = (t >> 3) & 255;
    int q  = t >> 11;
    int k  = q % 9, ci = q / 9;
    int r  = u >> 3;
    int v  = (u & 7) ^ (r & 7);
    int o  = 2 * r + (v >> 2);
    int g  = v & 3;
    int i  = ci * 32 + g * 8 + j;
    dst[t] = (__bf16)src[((size_t)o * 64 + i) * 9 + k];
}

// 1x1 W prep: f32 [64][64] -> bf16 [ci][256 units][8], packed+inv-swizzled
__device__ void prep1_body(int cb, const float* __restrict__ src,
                           __bf16* __restrict__ dst)
{
    int t = cb * 256 + threadIdx.x;
    if (t >= 2 * 2048) return;
    int j  = t & 7;
    int u  = (t >> 3) & 255;
    int ci = t >> 11;
    int r  = u >> 3;
    int v  = (u & 7) ^ (r & 7);
    int o  = 2 * r + (v >> 2);
    int g  = v & 3;
    int i  = ci * 32 + g * 8 + j;
    dst[t] = (__bf16)src[(size_t)o * 64 + i];
}

__device__ void prepF_body(int cb, const float* __restrict__ mt,
                           const float* __restrict__ aw, __bf16* __restrict__ dst)
{
    int t = cb * 256 + threadIdx.x;
    if (t >= 2 * 25 * 3072) return;
    int j  = t & 7;
    int u  = (t >> 3) % 384;
    int q  = t / 3072;
    int k  = q % 25, ci = q / 25;
    int r  = u >> 3;
    int v  = (u & 7) ^ (r & 7);
    int o  = 2 * r + (v >> 2);
    int g  = v & 3;
    int i  = ci * 32 + g * 8 + j;
    float val = 0.f;
    if (o < 64)      val = mt[((size_t)o * 64 + i) * 25 + k];
    else if (o < 73) val = aw[((size_t)(o - 64) * 64 + i) * 25 + k];
    dst[t] = (__bf16)val;
}

// prep super-kernel. Grid 2528.
__global__ __launch_bounds__(256) void k_prep(
    const float* x, const float* mask,
    const float* c1w, const float* c2w,
    const float* mt1w, const float* aw1w,
    const float* mt2w, const float* aw2w,
    const float* crw,
    __bf16* xh, __bf16* mh,
    __bf16* wbc1, __bf16* wbc2, __bf16* wbF1, __bf16* wbF2, __bf16* wbcr)
{
    int bid = blockIdx.x;
    if      (bid < 512)  cvt_body(bid, x, xh);
    else if (bid < 1024) cvt_body(bid - 512, mask, mh);
    else if (bid < 1168) prep3_body(bid - 1024, c1w, wbc1);
    else if (bid < 1312) prep3_body(bid - 1168, c2w, wbc2);
    else if (bid < 1912) prepF_body(bid - 1312, mt1w, aw1w, wbF1);
    else if (bid < 2512) prepF_body(bid - 1912, mt2w, aw2w, wbF2);
    else                 prep1_body(bid - 2512, crw, wbcr);
}

// ---------------------------------------------------------------------------
// Fused 5x5 MFMA conv (mt 64ch + aw 9ch), ci-split, W double-buffered via
// async global_load_lds + counted vmcnt. EPI=0: bf16 NHWC; EPI=1: f32 NCHW.
// ---------------------------------------------------------------------------
template<int EPI>
__global__ __launch_bounds__(256) void k_conv5(
    const __bf16* __restrict__ xh, const __bf16* __restrict__ wb,
    const float* __restrict__ bias, const float* __restrict__ bias2,
    float* __restrict__ outf, __bf16* __restrict__ outh,
    float* __restrict__ out2)
{
    constexpr int TW    = 20;
    constexpr int NPIX  = 400;
    constexpr int KK    = 25;
    constexpr int SROWS = 96;
    constexpr int SLICE = SROWS * 64;
    constexpr int NPIX2 = NPIX / 2;
    constexpr int MFT   = 5;

    __shared__ __align__(16) __bf16 lx[NPIX2 * 64];
    __shared__ __align__(16) __bf16 lw[2][SROWS * 32];
    __shared__ float lb[80];

    const int t    = threadIdx.x;
    const int w0   = blockIdx.x * 16, h0 = blockIdx.y * 16, b = blockIdx.z;
    const int wvv  = t >> 6;
    const int lane = t & 63;
    const int px   = lane & 15;
    const int g    = lane >> 4;

    auto STAGE = [&](int ci, int k, int buf) {
        const char* gs = (const char*)wb + (size_t)(ci * KK + k) * SLICE;
        if (wvv < 3) {
            #pragma unroll
            for (int r = 0; r < 2; ++r) {
                int ub = wvv * 128 + r * 64;
                gload_lds16(gs + (ub + lane) * 16, (char*)lw[buf] + ub * 16);
            }
        }
    };

    f32x4 acc[MFT][4];
    #pragma unroll
    for (int m = 0; m < MFT; ++m)
        #pragma unroll
        for (int nf = 0; nf < 4; ++nf)
            acc[m][nf] = (f32x4){0.f, 0.f, 0.f, 0.f};

    bf16x8 zv;
    #pragma unroll
    for (int j = 0; j < 8; ++j) zv[j] = (__bf16)0.f;

    for (int ci = 0; ci < 2; ++ci) {
        if (ci) __syncthreads();
        STAGE(ci, 0, 0);
        STAGE(ci, 1, 1);
        if (ci == 0) {
            if (t < 64) lb[t] = bias[t];
            if (t >= 64 && t < 80) lb[t] = (t - 64 < 9) ? bias2[t - 64] : 0.f;
        }

        #pragma unroll
        for (int xi = 0; xi < 7; ++xi) {
            int e = xi * 256 + t;
            if (e < NPIX * 4) {
                int pix = e >> 2, c4 = e & 3;
                int sy = pix / TW, sx = pix - sy * TW;
                int gy = h0 + sy - 2, gx = w0 + sx - 2;
                bool ok = (unsigned)gy < 256u && (unsigned)gx < 256u;
                bf16x8 v8 = zv;
                if (ok) v8 = *(const bf16x8*)(xh + ((((size_t)b << 16) + gy * 256 + gx) << 6)
                                              + ci * 32 + c4 * 8);
                int row = pix >> 1;
                int off = row * 128 + (((((pix & 1) << 2) + c4) ^ (row & 7)) << 4);
                *(bf16x8*)((char*)lx + off) = v8;
            }
        }
        __syncthreads();

        #pragma unroll
        for (int k = 0; k < KK; ++k) {
            const __bf16* lwb = (k & 1) ? lw[1] : lw[0];
            const int dy = k / 5, dx = k - dy * 5;

            bf16x8 bfr[4];
            #pragma unroll
            for (int nf = 0; nf < 4; ++nf) {
                int pix = (wvv * 4 + nf + dy) * TW + (px + dx);
                int row = pix >> 1;
                int off = row * 128 + (((((pix & 1) << 2) + g) ^ (row & 7)) << 4);
                bfr[nf] = *(const bf16x8*)((const char*)lx + off);
            }
            bf16x8 afr[MFT];
            #pragma unroll
            for (int m = 0; m < MFT; ++m) {
                int o = m * 16 + px;
                int row = o >> 1;
                int off = row * 128 + (((((o & 1) << 2) + g) ^ (row & 7)) << 4);
                afr[m] = *(const bf16x8*)((const char*)lwb + off);
            }
            __builtin_amdgcn_s_setprio(1);
            #pragma unroll
            for (int m = 0; m < MFT; ++m)
                #pragma unroll
                for (int nf = 0; nf < 4; ++nf)
                    acc[m][nf] = __builtin_amdgcn_mfma_f32_16x16x32_bf16(
                        afr[m], bfr[nf], acc[m][nf], 0, 0, 0);
            __builtin_amdgcn_s_setprio(0);

            if (k == KK - 1) break;

            asm volatile("s_waitcnt lgkmcnt(0)" ::: "memory");
            __builtin_amdgcn_sched_barrier(0);
            __builtin_amdgcn_s_barrier();
            bool issued = (k + 2 < KK);
            if (issued) STAGE(ci, k + 2, k & 1);
            if (issued && wvv < 3) asm volatile("s_waitcnt vmcnt(2)" ::: "memory");
            else                   asm volatile("s_waitcnt vmcnt(0)" ::: "memory");
            __builtin_amdgcn_sched_barrier(0);
            __builtin_amdgcn_s_barrier();
        }
    }

    #pragma unroll
    for (int m = 0; m < MFT; ++m) {
        #pragma unroll
        for (int nf = 0; nf < 4; ++nf) {
            int row = h0 + wvv * 4 + nf, col = w0 + px;
            if (m < 4) {
                float vj[4];
                #pragma unroll
                for (int j = 0; j < 4; ++j) {
                    float v = acc[m][nf][j] + lb[m * 16 + g * 4 + j];
                    vj[j] = v > 0.f ? v : 0.01f * v;
                }
                if constexpr (EPI == 0) {
                    bf16x4 pk;
                    #pragma unroll
                    for (int j = 0; j < 4; ++j) pk[j] = (__bf16)vj[j];
                    *(bf16x4*)(outh + ((((size_t)b << 16) + row * 256 + col) << 6)
                                    + m * 16 + g * 4) = pk;
                } else {
                    #pragma unroll
                    for (int j = 0; j < 4; ++j)
                        outf[((size_t)(b * 64 + m * 16 + g * 4 + j) << 16)
                             + row * 256 + col] = vj[j];
                }
            } else {
                #pragma unroll
                for (int j = 0; j < 4; ++j) {
                    int o2 = g * 4 + j;
                    if (o2 < 9)
                        out2[((size_t)(b * 9 + o2) << 16) + row * 256 + col]
                            = acc[m][nf][j] + lb[64 + o2];
                }
            }
        }
    }
}

// ---------------------------------------------------------------------------
// 3x3 MFMA conv, ci-split, ALL 9 W slices staged per phase -> zero in-loop
// barriers. bf16 NHWC out.
// ---------------------------------------------------------------------------
__global__ __launch_bounds__(256) void k_conv3(
    const __bf16* __restrict__ xh, const __bf16* __restrict__ wb,
    const float* __restrict__ bias, __bf16* __restrict__ outh)
{
    constexpr int TW    = 18;
    constexpr int NPIX  = 324;
    constexpr int NPIX2 = 162;

    __shared__ __align__(16) __bf16 lx[NPIX2 * 64];
    __shared__ __align__(16) __bf16 lw[9 * 2048];
    __shared__ float lb[64];

    const int t    = threadIdx.x;
    const int w0   = blockIdx.x * 16, h0 = blockIdx.y * 16, b = blockIdx.z;
    const int wvv  = t >> 6;
    const int lane = t & 63;
    const int px   = lane & 15;
    const int g    = lane >> 4;

    f32x4 acc[4][4];
    #pragma unroll
    for (int m = 0; m < 4; ++m)
        #pragma unroll
        for (int nf = 0; nf < 4; ++nf)
            acc[m][nf] = (f32x4){0.f, 0.f, 0.f, 0.f};

    bf16x8 zv;
    #pragma unroll
    for (int j = 0; j < 8; ++j) zv[j] = (__bf16)0.f;

    for (int ci = 0; ci < 2; ++ci) {
        if (ci) __syncthreads();
        {
            const char* gs = (const char*)wb + (size_t)ci * 9 * 4096;
            #pragma unroll
            for (int r = 0; r < 9; ++r) {
                int ub = r * 256 + wvv * 64;
                gload_lds16(gs + (ub + lane) * 16, (char*)lw + ub * 16);
            }
        }
        if (ci == 0 && t < 64) lb[t] = bias[t];

        #pragma unroll
        for (int xi = 0; xi < 6; ++xi) {
            int e = xi * 256 + t;
            if (e < NPIX * 4) {
                int pix = e >> 2, c4 = e & 3;
                int sy = pix / TW, sx = pix - sy * TW;
                int gy = h0 + sy - 1, gx = w0 + sx - 1;
                bool ok = (unsigned)gy < 256u && (unsigned)gx < 256u;
                bf16x8 v8 = zv;
                if (ok) v8 = *(const bf16x8*)(xh + ((((size_t)b << 16) + gy * 256 + gx) << 6)
                                              + ci * 32 + c4 * 8);
                int row = pix >> 1;
                int off = row * 128 + (((((pix & 1) << 2) + c4) ^ (row & 7)) << 4);
                *(bf16x8*)((char*)lx + off) = v8;
            }
        }
        __syncthreads();

        #pragma unroll
        for (int k = 0; k < 9; ++k) {
            const __bf16* lwb = lw + k * 2048;
            const int dy = k / 3, dx = k - dy * 3;

            bf16x8 bfr[4];
            #pragma unroll
            for (int nf = 0; nf < 4; ++nf) {
                int pix = (wvv * 4 + nf + dy) * TW + (px + dx);
                int row = pix >> 1;
                int off = row * 128 + (((((pix & 1) << 2) + g) ^ (row & 7)) << 4);
                bfr[nf] = *(const bf16x8*)((const char*)lx + off);
            }
            bf16x8 afr[4];
            #pragma unroll
            for (int m = 0; m < 4; ++m) {
                int o = m * 16 + px;
                int row = o >> 1;
                int off = row * 128 + (((((o & 1) << 2) + g) ^ (row & 7)) << 4);
                afr[m] = *(const bf16x8*)((const char*)lwb + off);
            }
            __builtin_amdgcn_s_setprio(1);
            #pragma unroll
            for (int m = 0; m < 4; ++m)
                #pragma unroll
                for (int nf = 0; nf < 4; ++nf)
                    acc[m][nf] = __builtin_amdgcn_mfma_f32_16x16x32_bf16(
                        afr[m], bfr[nf], acc[m][nf], 0, 0, 0);
            __builtin_amdgcn_s_setprio(0);
        }
    }

    #pragma unroll
    for (int m = 0; m < 4; ++m) {
        #pragma unroll
        for (int nf = 0; nf < 4; ++nf) {
            int row = h0 + wvv * 4 + nf, col = w0 + px;
            bf16x4 pk;
            #pragma unroll
            for (int j = 0; j < 4; ++j) {
                float v = acc[m][nf][j] + lb[m * 16 + g * 4 + j];
                pk[j] = (__bf16)v;
            }
            *(bf16x4*)(outh + ((((size_t)b << 16) + row * 256 + col) << 6)
                            + m * 16 + g * 4) = pk;
        }
    }
}

// ---------------------------------------------------------------------------
// 1x1 residual conv via MFMA (KSZ=1 variant of conv3): no halo, 1 k-step,
// 20.6KB LDS. res = conv1x1(xh) + crb -> bf16 NHWC.
// ---------------------------------------------------------------------------
__global__ __launch_bounds__(256) void k_conv1(
    const __bf16* __restrict__ xh, const __bf16* __restrict__ wb,
    const float* __restrict__ bias, __bf16* __restrict__ outh)
{
    constexpr int NPIX2 = 128;

    __shared__ __align__(16) __bf16 lx[NPIX2 * 64];   // 16KB
    __shared__ __align__(16) __bf16 lw[2048];         // 4KB (one ci slice)
    __shared__ float lb[64];

    const int t    = threadIdx.x;
    const int w0   = blockIdx.x * 16, h0 = blockIdx.y * 16, b = blockIdx.z;
    const int wvv  = t >> 6;
    const int lane = t & 63;
    const int px   = lane & 15;
    const int g    = lane >> 4;

    f32x4 acc[4][4];
    #pragma unroll
    for (int m = 0; m < 4; ++m)
        #pragma unroll
        for (int nf = 0; nf < 4; ++nf)
            acc[m][nf] = (f32x4){0.f, 0.f, 0.f, 0.f};

    for (int ci = 0; ci < 2; ++ci) {
        if (ci) __syncthreads();
        {
            const char* gs = (const char*)wb + (size_t)ci * 4096;
            int ub = wvv * 64;
            gload_lds16(gs + (ub + lane) * 16, (char*)lw + ub * 16);
        }
        if (ci == 0 && t < 64) lb[t] = bias[t];

        // stage 16x16 x tile (no halo; always in bounds)
        #pragma unroll
        for (int xi = 0; xi < 4; ++xi) {
            int e = xi * 256 + t;
            int pix = e >> 2, c4 = e & 3;
            int gy = h0 + (pix >> 4), gx = w0 + (pix & 15);
            bf16x8 v8 = *(const bf16x8*)(xh + ((((size_t)b << 16) + gy * 256 + gx) << 6)
                                         + ci * 32 + c4 * 8);
            int row = pix >> 1;
            int off = row * 128 + (((((pix & 1) << 2) + c4) ^ (row & 7)) << 4);
            *(bf16x8*)((char*)lx + off) = v8;
        }
        __syncthreads();

        bf16x8 bfr[4];
        #pragma unroll
        for (int nf = 0; nf < 4; ++nf) {
            int pix = (wvv * 4 + nf) * 16 + px;
            int row = pix >> 1;
            int off = row * 128 + (((((pix & 1) << 2) + g) ^ (row & 7)) << 4);
            bfr[nf] = *(const bf16x8*)((const char*)lx + off);
        }
        bf16x8 afr[4];
        #pragma unroll
        for (int m = 0; m < 4; ++m) {
            int o = m * 16 + px;
            int row = o >> 1;
            int off = row * 128 + (((((o & 1) << 2) + g) ^ (row & 7)) << 4);
            afr[m] = *(const bf16x8*)((const char*)lw + off);
        }
        #pragma unroll
        for (int m = 0; m < 4; ++m)
            #pragma unroll
            for (int nf = 0; nf < 4; ++nf)
                acc[m][nf] = __builtin_amdgcn_mfma_f32_16x16x32_bf16(
                    afr[m], bfr[nf], acc[m][nf], 0, 0, 0);
    }

    #pragma unroll
    for (int m = 0; m < 4; ++m) {
        #pragma unroll
        for (int nf = 0; nf < 4; ++nf) {
            int row = h0 + wvv * 4 + nf, col = w0 + px;
            bf16x4 pk;
            #pragma unroll
            for (int j = 0; j < 4; ++j)
                pk[j] = (__bf16)(acc[m][nf][j] + lb[m * 16 + g * 4 + j]);
            *(bf16x4*)(outh + ((((size_t)b << 16) + row * 256 + col) << 6)
                            + m * 16 + g * 4) = pk;
        }
    }
}

// ---------------------------------------------------------------------------
// Adaptive einsum, coalesced: 8 threads/pixel. -> bf16 NHWC.
// ---------------------------------------------------------------------------
__global__ __launch_bounds__(256, 4) void k_ada1(
    const float* __restrict__ wgt, const __bf16* __restrict__ xin,
    __bf16* __restrict__ outh)
{
    int t  = threadIdx.x;
    int pg = t >> 3, c8 = t & 7;
    int p  = blockIdx.x * 32 + pg;
    int b  = p >> 16, hw = p & 65535;
    int h  = hw >> 8, wc = hw & 255;

    const float* wp = wgt + ((size_t)(b * 9) << 16) + hw;
    const __bf16* cen = xin + (size_t)p * 64 + c8 * 8;

    float wk[9];
    const __bf16* nbp[9];
    #pragma unroll
    for (int dy = 0; dy < 3; ++dy)
        #pragma unroll
        for (int dx = 0; dx < 3; ++dx) {
            int k = dy * 3 + dx;
            bool ok = ((unsigned)(h + dy - 1) < 256u) &&
                      ((unsigned)(wc + dx - 1) < 256u);
            wk[k]  = ok ? wp[(size_t)k << 16] : 0.f;
            nbp[k] = ok ? cen + ((dy - 1) * 256 + (dx - 1)) * 64 : cen;
        }

    float acc[8] = {0.f,0.f,0.f,0.f,0.f,0.f,0.f,0.f};
    #pragma unroll
    for (int k = 0; k < 9; ++k) {
        bf16x8 v8 = *(const bf16x8*)nbp[k];
        float w = wk[k];
        #pragma unroll
        for (int j = 0; j < 8; ++j) acc[j] += w * (float)v8[j];
    }

    bf16x8 o8;
    #pragma unroll
    for (int j = 0; j < 8; ++j) {
        float v = acc[j];
        o8[j] = (__bf16)(v > 0.f ? v : 0.01f * v);
    }
    *(bf16x8*)(outh + (size_t)p * 64 + c8 * 8) = o8;
}

// ---------------------------------------------------------------------------
// Final adaptive einsum: lrelu(ada) + res (bf16 NHWC, contiguous load in
// phase 1), pure-write f32 NCHW out via LDS transpose.
// ---------------------------------------------------------------------------
__global__ __launch_bounds__(256, 4) void k_ada2(
    const float* __restrict__ wgt, const __bf16* __restrict__ x2h,
    const __bf16* __restrict__ resh, float* __restrict__ outf)
{
    __shared__ float ls[32 * 65];

    int t  = threadIdx.x;
    int pg = t >> 3, c8 = t & 7;
    int p  = blockIdx.x * 32 + pg;
    int b  = p >> 16, hw = p & 65535;
    int h  = hw >> 8, wc = hw & 255;

    const float* wp = wgt + ((size_t)(b * 9) << 16) + hw;
    const __bf16* cen = x2h + (size_t)p * 64 + c8 * 8;

    float wk[9];
    const __bf16* nbp[9];
    #pragma unroll
    for (int dy = 0; dy < 3; ++dy)
        #pragma unroll
        for (int dx = 0; dx < 3; ++dx) {
            int k = dy * 3 + dx;
            bool ok = ((unsigned)(h + dy - 1) < 256u) &&
                      ((unsigned)(wc + dx - 1) < 256u);
            wk[k]  = ok ? wp[(size_t)k << 16] : 0.f;
            nbp[k] = ok ? cen + ((dy - 1) * 256 + (dx - 1)) * 64 : cen;
        }

    float acc[8] = {0.f,0.f,0.f,0.f,0.f,0.f,0.f,0.f};
    #pragma unroll
    for (int k = 0; k < 9; ++k) {
        bf16x8 v8 = *(const bf16x8*)nbp[k];
        float w = wk[k];
        #pragma unroll
        for (int j = 0; j < 8; ++j) acc[j] += w * (float)v8[j];
    }

    // + residual (bf16 NHWC, contiguous 16B per lane)
    bf16x8 r8 = *(const bf16x8*)(resh + (size_t)p * 64 + c8 * 8);
    #pragma unroll
    for (int j = 0; j < 8; ++j) {
        float v = acc[j];
        v = v > 0.f ? v : 0.01f * v;
        ls[pg * 65 + c8 * 8 + j] = v + (float)r8[j];
    }
    __syncthreads();

    int pbase = blockIdx.x * 32;
    int bb    = pbase >> 16, hwb = pbase & 65535;
    int pix   = t & 31, cq = t >> 5;
    #pragma unroll
    for (int i = 0; i < 8; ++i) {
        int c = i * 8 + cq;
        size_t oi = ((size_t)(bb * 64 + c) << 16) + hwb + pix;
        outf[oi] = ls[pix * 65 + c];
    }
}

// ---------------------------------------------------------------------------
// Buffer plan (ws use = 55.8 MB):
//   wgt   f32  @0           4,718,592   adaptive weights (F1->ada1, F2->ada2)
//   xh    bf16 @4,718,592  16,777,216   x NHWC
//   mh    bf16 @21,495,808 16,777,216   mask NHWC; x2h reuses after F1
//   wb    bf16 @38,273,024    770,048   prepped conv weights (+1x1)
//   resh  bf16 @39,043,072 16,777,216   residual, bf16 NHWC (conv1 -> ada2)
// d_out scratch: out_x lower = maska_h, out_x upper = xa_h, out_m = x1_h.
// Launches: prep -> F1 -> c3_1 -> ada1 -> F2 -> c3_2 -> conv1 -> ada2.
// ---------------------------------------------------------------------------
extern "C" void kernel_launch(void* const* d_in, const int* in_sizes, int n_in,
                              void* d_out, int out_size, void* d_ws, size_t ws_size,
                              hipStream_t stream)
{
    const float* x     = (const float*)d_in[0];
    const float* mask  = (const float*)d_in[1];
    const float* aw1_w = (const float*)d_in[2];
    const float* aw1_b = (const float*)d_in[3];
    const float* mt1_w = (const float*)d_in[4];
    const float* mt1_b = (const float*)d_in[5];
    const float* c1_w  = (const float*)d_in[6];
    const float* c1_b  = (const float*)d_in[7];
    const float* aw2_w = (const float*)d_in[8];
    const float* aw2_b = (const float*)d_in[9];
    const float* mt2_w = (const float*)d_in[10];
    const float* mt2_b = (const float*)d_in[11];
    const float* c2_w  = (const float*)d_in[12];
    const float* c2_b  = (const float*)d_in[13];
    const float* cr_w  = (const float*)d_in[14];
    const float* cr_b  = (const float*)d_in[15];

    float* out_x = (float*)d_out;
    float* out_m = (float*)d_out + 8388608;

    float*  wgt   = (float*)d_ws;
    __bf16* xh    = (__bf16*)((char*)d_ws + 4718592);
    __bf16* mh    = (__bf16*)((char*)d_ws + 21495808);
    __bf16* x2h   = mh;                                // sequential live ranges
    __bf16* wbase = (__bf16*)((char*)d_ws + 38273024);
    __bf16* wb_c1 = wbase;             // 36864 elems
    __bf16* wb_c2 = wbase + 36864;     // 36864
    __bf16* wb_F1 = wbase + 73728;     // 153600
    __bf16* wb_F2 = wbase + 227328;    // 153600
    __bf16* wb_cr = wbase + 380928;    // 4096
    __bf16* resh  = (__bf16*)((char*)d_ws + 39043072);

    __bf16* maska_h = (__bf16*)out_x;               // lower 16.78 MB
    __bf16* xa_h    = (__bf16*)out_x + 8388608;     // upper 16.78 MB
    __bf16* x1_h    = (__bf16*)out_m;               // lower 16.78 MB

    dim3 blk(256);
    dim3 gconv(16, 16, 2);
    dim3 gada(4096);

    // 0. merged prep: layout conversions + weight preps (incl. 1x1 W)
    k_prep<<<dim3(2528), blk, 0, stream>>>(x, mask, c1_w, c2_w,
        mt1_w, aw1_w, mt2_w, aw2_w, cr_w,
        xh, mh, wb_c1, wb_c2, wb_F1, wb_F2, wb_cr);

    // 1. F1(mh): maska = lrelu(mt1) -> maska_h (bf16), weight1 = aw1 -> wgt
    k_conv5<0><<<gconv, blk, 0, stream>>>(mh, wb_F1, mt1_b, aw1_b,
                                          nullptr, maska_h, wgt);
    // 2. x1 = conv3x3(xh, c1) -> x1_h
    k_conv3<<<gconv, blk, 0, stream>>>(xh, wb_c1, c1_b, x1_h);
    // 3. xa = lrelu(ada(wgt, x1)) -> xa_h
    k_ada1<<<gada, blk, 0, stream>>>(wgt, x1_h, xa_h);
    // 4. F2(maska_h): final mask = lrelu(mt2) -> out_m (f32), weight2 -> wgt
    k_conv5<1><<<gconv, blk, 0, stream>>>(maska_h, wb_F2, mt2_b, aw2_b,
                                          out_m, nullptr, wgt);
    // 5. x2 = conv3x3(xa_h, c2) -> x2h
    k_conv3<<<gconv, blk, 0, stream>>>(xa_h, wb_c2, c2_b, x2h);
    // 6. res = conv1x1(xh) via MFMA -> resh (bf16 NHWC)
    k_conv1<<<gconv, blk, 0, stream>>>(xh, wb_cr, cr_b, resh);
    // 7. out_x = lrelu(ada(wgt, x2)) + res   (pure write)
    k_ada2<<<gada, blk, 0, stream>>>(wgt, x2h, resh, out_x);
}